// Round 5
// baseline (269.552 us; speedup 1.0000x reference)
//
#include <hip/hip_runtime.h>

// ---------------------------------------------------------------------------
// 2-layer GCN + global mean pool, MI355X (gfx950).
//   A_hat = D^{-1/2}(A+I)D^{-1/2}
//   G' = dinv*(X @ W1) fp16 [MFMA fp16];  H'' = dinv*relu(dinv*A_sum(G')+b1)
//   out = pool(dinv*A_sum(H'')) @ W2 + b2
// R15: panel-major aggregation (R12's locality idea on R13's burst structure).
//   Gh/Hh panel-major: 4 panels x 32 cols (64B/node/panel). agg blocks pin
//   panel = bid&3; round-robin bid->XCD gives each XCD a 3.2MB L2-resident
//   panel -> fabric gather traffic ~113MB -> ~26MB per layer. Bursts: 8
//   padded edges = 1 bcast colidx load + 2 gather instrs (4 edge-slots x
//   16 lanes), branchless; shfl_xor(16,32) reduce per node.
//   bucket_scan fused into bucket_deg via last-block ticket (-1 launch).
//   CSR build unchanged from R14 (zero global per-edge atomics).
// ws_size is 256 MiB; we use ~35 MB.
// ---------------------------------------------------------------------------

#define D 128
#define NGRAPH 64
#define AGG_BLOCKS 2048   // 8192 waves = 32/CU; 512 blocks per panel
#define NPAN 4
#define BUCK_SH 9         // bucket = dst >> 9 (width 512)
#define BUCK_W  512
#define MAXBUCK 128       // N <= 65536

typedef _Float16 h16x2 __attribute__((ext_vector_type(2)));
typedef _Float16 f16x8 __attribute__((ext_vector_type(8)));
typedef float    f32x4 __attribute__((ext_vector_type(4)));
typedef unsigned short u16x8 __attribute__((ext_vector_type(8)));

__device__ __forceinline__ float2 h2f(unsigned u) {
    h16x2 h = __builtin_bit_cast(h16x2, u);
    return make_float2((float)h.x, (float)h.y);
}
__device__ __forceinline__ unsigned f2h(float x, float y) {
    h16x2 h;
    h.x = (_Float16)x;
    h.y = (_Float16)y;
    return __builtin_bit_cast(unsigned, h);
}

// --- diagnostic: all-zero output (ws too small) ----------------------------
__global__ void zero_out_kernel(float* __restrict__ out, int n) {
    int i = blockIdx.x * blockDim.x + threadIdx.x;
    if (i < n) out[i] = 0.f;
}

// --- K1: W1 pack (blocks 0..7) | zero sentinel rows (block 8) | bucket
//     scatter (blocks 9..): LDS histogram + per-block span reservation. -----
__global__ __launch_bounds__(256) void pack_scatter_kernel(const float* __restrict__ W1,
                                                           _Float16* __restrict__ WB,
                                                           const int* __restrict__ ei,
                                                           int* __restrict__ bcnt,
                                                           unsigned* __restrict__ buck,
                                                           unsigned* __restrict__ Gz,
                                                           unsigned* __restrict__ Hz,
                                                           int N, int E, int CAP) {
    int b = (int)blockIdx.x;
    int t = (int)threadIdx.x;
    if (b < 8) {
        // WB[((kt*8+nt)*64+lane)*8+j] = W1[(kt*32+(lane>>4)*8+j)*D + nt*16+(lane&15)]
        int idx = b * 256 + t;                         // 0..2047
        int lane = idx & 63;
        int nt   = (idx >> 6) & 7;
        int kt   = idx >> 9;
        int col  = nt * 16 + (lane & 15);
        int krow = kt * 32 + (lane >> 4) * 8;
#pragma unroll
        for (int j = 0; j < 8; ++j)
            WB[idx * 8 + j] = (_Float16)W1[(krow + j) * D + col];
        return;
    }
    if (b == 8) {
        // zero sentinel row N in every panel (panel-major: row stride 16 dw)
        size_t Nrow = (size_t)N + 1;
        if (t < 64) {
            int p = t >> 4, k = t & 15;
            Gz[((size_t)p * Nrow + N) * 16 + k] = 0u;
        } else if (t < 128) {
            int q = t - 64, p = q >> 4, k = q & 15;
            Hz[((size_t)p * Nrow + N) * 16 + k] = 0u;
        }
        return;
    }
    __shared__ unsigned histL[MAXBUCK];
    __shared__ int      baseL[MAXBUCK];
    if (t < MAXBUCK) histL[t] = 0u;
    __syncthreads();

    int e0 = (b - 9) * 1024;
    int bid[4];
    unsigned lidx[4], pk[4];
#pragma unroll
    for (int j = 0; j < 4; ++j) {
        int e = e0 + t + j * 256;
        bid[j] = -1;
        if (e < E) {
            int s = ei[e];
            int d = ei[E + e];
            if (d >= 0 && d < N) {
                s = min(max(s, 0), N - 1);
                bid[j] = d >> BUCK_SH;
                pk[j]  = ((unsigned)d << 16) | (unsigned)s;
            }
        }
    }
#pragma unroll
    for (int j = 0; j < 4; ++j)
        if (bid[j] >= 0) lidx[j] = atomicAdd(&histL[bid[j]], 1u);
    __syncthreads();
    if (t < MAXBUCK && histL[t] > 0u)
        baseL[t] = atomicAdd(&bcnt[t], (int)histL[t]);
    __syncthreads();
#pragma unroll
    for (int j = 0; j < 4; ++j)
        if (bid[j] >= 0) {
            int slot = baseL[bid[j]] + (int)lidx[j];
            if (slot < CAP) buck[(size_t)bid[j] * CAP + slot] = pk[j];
        }
}

// --- K2: per-bucket degree count (LDS atomics) -> deg, dinv, padsum;
//     LAST block (ticket) also scans padsums -> bbase, rowstart[N]. ---------
__global__ __launch_bounds__(256) void bucket_deg_kernel(const unsigned* __restrict__ buck,
                                                         const int* __restrict__ bcnt,
                                                         int* __restrict__ deg,
                                                         float* __restrict__ dinv,
                                                         int* __restrict__ padsum,
                                                         int* __restrict__ bbase,
                                                         int* __restrict__ rowstart,
                                                         int* __restrict__ ticket,
                                                         int N, int CAP, int nbuck) {
    __shared__ int degL[BUCK_W];
    __shared__ int red[256];
    __shared__ int lastFlag;
    int b = (int)blockIdx.x;
    int t = (int)threadIdx.x;
    for (int k = t; k < BUCK_W; k += 256) degL[k] = 0;
    __syncthreads();
    int cnt = min(bcnt[b], CAP);
    const unsigned* bp = buck + (size_t)b * CAP;
    for (int i = t; i < cnt; i += 256)
        atomicAdd(&degL[(bp[i] >> 16) & (BUCK_W - 1)], 1);
    __syncthreads();
    int base = b << BUCK_SH;
    int local = 0;
    for (int k = t; k < BUCK_W; k += 256) {
        int d = base + k;
        if (d < N) {
            int dg = degL[k];
            deg[d]  = dg;
            dinv[d] = rsqrtf((float)dg + 1.0f);
            local  += (dg + 7) & ~7;
        }
    }
    red[t] = local;
    __syncthreads();
    for (int off = 128; off > 0; off >>= 1) {
        if (t < off) red[t] += red[t + off];
        __syncthreads();
    }
    if (t == 0) padsum[b] = red[0];
    __threadfence();
    if (t == 0) lastFlag = (atomicAdd(ticket, 1) == nbuck - 1) ? 1 : 0;
    __syncthreads();
    if (lastFlag) {
        __threadfence();                     // acquire all padsum writes
        __shared__ int s[128];
        int own = (t < nbuck) ? padsum[t] : 0;
        if (t < 128) s[t] = own;
        __syncthreads();
        for (int off = 1; off < 128; off <<= 1) {
            int v = (t < 128 && t >= off) ? s[t - off] : 0;
            __syncthreads();
            if (t < 128) s[t] += v;
            __syncthreads();
        }
        if (t < nbuck) bbase[t] = s[t] - own;        // exclusive
        if (t == 127) rowstart[N] = s[127];
    }
}

// --- K3: fused MFMA GEMM (blocks [0,gb)) + bucket CSR fill ([gb,gb+nbuck)) -
// GEMM writes Gh PANEL-MAJOR. Fill: per-bucket LDS scan -> rowstart,
// sentinel pads, colidx via LDS cursors. Zero global atomics.
__global__ __launch_bounds__(256) void gemm_fill_kernel(const float* __restrict__ X,
                                                        const _Float16* __restrict__ WB,
                                                        const float* __restrict__ dinv,
                                                        _Float16* __restrict__ Gh,
                                                        const unsigned* __restrict__ buck,
                                                        const int* __restrict__ bcnt,
                                                        const int* __restrict__ deg,
                                                        const int* __restrict__ bbase,
                                                        int* __restrict__ rowstart,
                                                        unsigned short* __restrict__ colidx,
                                                        int N, int CAP, int gb) {
    if ((int)blockIdx.x >= gb) {
        __shared__ int degS[BUCK_W];    // deg, later absolute cursors
        __shared__ int loff[BUCK_W];
        __shared__ int sc[256];
        int b = (int)blockIdx.x - gb;
        int t = (int)threadIdx.x;
        int base_d = b << BUCK_SH;
        for (int k = t; k < BUCK_W; k += 256) {
            int d = base_d + k;
            degS[k] = (d < N) ? deg[d] : 0;
        }
        __syncthreads();
        // scan pad8 over 512 entries: thread t owns 2t, 2t+1
        int p0 = (degS[2 * t] + 7) & ~7;
        int p1 = (degS[2 * t + 1] + 7) & ~7;
        int own = p0 + p1;
        sc[t] = own;
        __syncthreads();
        for (int off = 1; off < 256; off <<= 1) {
            int v = (t >= off) ? sc[t - off] : 0;
            __syncthreads();
            sc[t] += v;
            __syncthreads();
        }
        int excl = sc[t] - own;
        loff[2 * t]     = excl;
        loff[2 * t + 1] = excl + p0;
        __syncthreads();
        int bb = bbase[b];
        // rowstart + sentinel pads (uses degS as degrees still)
        for (int k = t; k < BUCK_W; k += 256) {
            int d = base_d + k;
            if (d < N) {
                int rs = bb + loff[k];
                rowstart[d] = rs;
                int dg = degS[k];
                int p8 = (dg + 7) & ~7;
                for (int j = dg; j < p8; ++j)
                    colidx[rs + j] = (unsigned short)N;   // sentinel -> zero row
            }
        }
        __syncthreads();
        // convert degS -> absolute cursors
        for (int k = t; k < BUCK_W; k += 256) degS[k] = bb + loff[k];
        __syncthreads();
        int cnt = min(bcnt[b], CAP);
        const unsigned* bp = buck + (size_t)b * CAP;
        for (int i = t; i < cnt; i += 256) {
            unsigned u = bp[i];
            int ld = (int)((u >> 16) & (BUCK_W - 1));
            int slot = atomicAdd(&degS[ld], 1);           // LDS atomic
            colidx[slot] = (unsigned short)(u & 0xffffu);
        }
        return;
    }

    int t = (int)threadIdx.x;
    int wave = t >> 6, lane = t & 63;
    int mbase = blockIdx.x * 64 + wave * 16;
    int arow  = mbase + (lane & 15);
    if (arow >= N) arow = N - 1;             // clamped duplicate reads
    int kgrp  = lane >> 4;                   // 0..3

    // A-frag: lane holds X[arow][kt*32 + kgrp*8 .. +8], converted to fp16
    f16x8 afrag[4];
#pragma unroll
    for (int kt = 0; kt < 4; ++kt) {
        const float* xp = X + (size_t)arow * D + kt * 32 + kgrp * 8;
        float4 a0 = *(const float4*)xp;
        float4 a1 = *(const float4*)(xp + 4);
        f16x8 af;
        af[0] = (_Float16)a0.x; af[1] = (_Float16)a0.y;
        af[2] = (_Float16)a0.z; af[3] = (_Float16)a0.w;
        af[4] = (_Float16)a1.x; af[5] = (_Float16)a1.y;
        af[6] = (_Float16)a1.z; af[7] = (_Float16)a1.w;
        afrag[kt] = af;
    }
    f32x4 acc[8];
#pragma unroll
    for (int nt = 0; nt < 8; ++nt) acc[nt] = (f32x4){0.f, 0.f, 0.f, 0.f};
#pragma unroll
    for (int kt = 0; kt < 4; ++kt) {
#pragma unroll
        for (int nt = 0; nt < 8; ++nt) {
            uint4 u = *(const uint4*)(WB + (((kt * 8 + nt) * 64 + lane) * 8));
            f16x8 bfrag = __builtin_bit_cast(f16x8, u);
            acc[nt] = __builtin_amdgcn_mfma_f32_16x16x32_f16(afrag[kt], bfrag, acc[nt], 0, 0, 0);
        }
    }
    // C/D: col = lane&15, row = kgrp*4 + reg   [m89-verified, dtype-indep]
    // panel-major store: panel = nt>>1, within-panel col = (nt&1)*16 + c16
    size_t Nrow = (size_t)N + 1;
    int r0 = mbase + kgrp * 4;
#pragma unroll
    for (int r = 0; r < 4; ++r) {
        int row = r0 + r;
        if (row < N) {
            float dv = dinv[row];
#pragma unroll
            for (int nt = 0; nt < 8; ++nt) {
                size_t adr = ((size_t)(nt >> 1) * Nrow + row) * 32 + (nt & 1) * 16 + (lane & 15);
                Gh[adr] = (_Float16)(dv * acc[nt][r]);
            }
        }
    }
}

// --- agg1: H''_i = dinv_i * relu(dinv_i*(sum_e G'_s + G'_i) + b1), fp16 -----
// Panel-pinned (p = bid&3), padded branchless bursts: 8 edges = 1 bcast
// colidx load + 2 gather instrs (4 edge-slots x 16 lanes x 4B = 64B/edge).
__global__ __launch_bounds__(256) void agg1_kernel(const unsigned* __restrict__ Gp,
                                                   const int* __restrict__ rowstart,
                                                   const unsigned short* __restrict__ colidx,
                                                   const float* __restrict__ dinv,
                                                   const float* __restrict__ b1,
                                                   unsigned* __restrict__ Hp,
                                                   int N, int chunk) {
    int bid  = (int)blockIdx.x;
    int p    = bid & (NPAN - 1);
    int gid  = (bid >> 2) * 4 + ((int)threadIdx.x >> 6);
    int lane = (int)threadIdx.x & 63;
    int eq   = lane >> 4;         // edge slot 0..3
    int cl   = lane & 15;         // 2 fp16 cols per lane
    size_t Nrow = (size_t)N + 1;
    const unsigned* P = Gp + (size_t)p * Nrow * 16;
    unsigned*       H = Hp + (size_t)p * Nrow * 16;
    float bx = b1[p * 32 + 2 * cl], by = b1[p * 32 + 2 * cl + 1];
    int i0 = gid * chunk, i1 = min(i0 + chunk, N);
    if (i0 >= N) return;
    int e = rowstart[i0];
    for (int i = i0; i < i1; ++i) {
        float di = dinv[i];
        int e1 = rowstart[i + 1];
        float2 acc = make_float2(0.f, 0.f);
        if (eq == 0) {                              // self term
            float2 v = h2f(P[(size_t)i * 16 + cl]);
            acc.x = v.x; acc.y = v.y;
        }
        for (; e < e1; e += 8) {                    // 8 edges: 2 gathers
            u16x8 cc = *(const u16x8*)(colidx + e); // bcast 16B
            int cA = (int)cc[eq];
            int cB = (int)cc[eq + 4];
            unsigned uA = P[(size_t)cA * 16 + cl];
            unsigned uB = P[(size_t)cB * 16 + cl];
            float2 vA = h2f(uA), vB = h2f(uB);
            acc.x += vA.x + vB.x;
            acc.y += vA.y + vB.y;
        }
        // reduce the 4 edge-slot groups (same cl)
        acc.x += __shfl_xor(acc.x, 16);
        acc.x += __shfl_xor(acc.x, 32);
        acc.y += __shfl_xor(acc.y, 16);
        acc.y += __shfl_xor(acc.y, 32);
        if (eq == 0) {
            float hx = fmaxf(fmaf(di, acc.x, bx), 0.f) * di;
            float hy = fmaxf(fmaf(di, acc.y, by), 0.f) * di;
            H[(size_t)i * 16 + cl] = f2h(hx, hy);
        }
    }
}

// --- agg2 + pool: pool[batch_i] += dinv_i*(sum_e H''_s + H''_i) -------------
__global__ __launch_bounds__(256) void agg2_pool_kernel(const unsigned* __restrict__ Hp,
                                                        const int* __restrict__ rowstart,
                                                        const unsigned short* __restrict__ colidx,
                                                        const float* __restrict__ dinv,
                                                        const int* __restrict__ batch,
                                                        float* __restrict__ pool,
                                                        int N, int chunk) {
    int bid  = (int)blockIdx.x;
    int p    = bid & (NPAN - 1);
    int gid  = (bid >> 2) * 4 + ((int)threadIdx.x >> 6);
    int lane = (int)threadIdx.x & 63;
    int eq   = lane >> 4;
    int cl   = lane & 15;
    size_t Nrow = (size_t)N + 1;
    const unsigned* P = Hp + (size_t)p * Nrow * 16;
    int i0 = gid * chunk, i1 = min(i0 + chunk, N);
    if (i0 >= N) return;

    float2 pa = make_float2(0.f, 0.f);
    int cur = min(max(batch[i0], 0), NGRAPH - 1);
    int e = rowstart[i0];
    for (int i = i0; i < i1; ++i) {
        float di = dinv[i];
        int e1 = rowstart[i + 1];
        float2 acc = make_float2(0.f, 0.f);
        if (eq == 0) {                              // self term
            float2 v = h2f(P[(size_t)i * 16 + cl]);
            acc.x = v.x; acc.y = v.y;
        }
        for (; e < e1; e += 8) {
            u16x8 cc = *(const u16x8*)(colidx + e);
            int cA = (int)cc[eq];
            int cB = (int)cc[eq + 4];
            unsigned uA = P[(size_t)cA * 16 + cl];
            unsigned uB = P[(size_t)cB * 16 + cl];
            float2 vA = h2f(uA), vB = h2f(uB);
            acc.x += vA.x + vB.x;
            acc.y += vA.y + vB.y;
        }
        acc.x += __shfl_xor(acc.x, 16);
        acc.x += __shfl_xor(acc.x, 32);
        acc.y += __shfl_xor(acc.y, 16);
        acc.y += __shfl_xor(acc.y, 32);

        int b = min(max(batch[i], 0), NGRAPH - 1);
        if (b != cur) {                             // uniform across wave
            if (eq == 0) {
                atomicAdd(&pool[(size_t)cur * D + p * 32 + 2 * cl],     pa.x);
                atomicAdd(&pool[(size_t)cur * D + p * 32 + 2 * cl + 1], pa.y);
            }
            pa = make_float2(0.f, 0.f);
            cur = b;
        }
        pa.x = fmaf(di, acc.x, pa.x);
        pa.y = fmaf(di, acc.y, pa.y);
    }
    if (eq == 0) {
        atomicAdd(&pool[(size_t)cur * D + p * 32 + 2 * cl],     pa.x);
        atomicAdd(&pool[(size_t)cur * D + p * 32 + 2 * cl + 1], pa.y);
    }
}

// --- Final tiny GEMM: out[g][o] = (pool[g]/cnt_g) . W2[:,o] + b2[o] ---------
__device__ __forceinline__ int lbound(const int* __restrict__ a, int n, int v) {
    int lo = 0, hi = n;
    while (lo < hi) {
        int m = (lo + hi) >> 1;
        if (a[m] < v) lo = m + 1; else hi = m;
    }
    return lo;
}

__global__ void final_gemm_kernel(const float* __restrict__ pool,
                                  const int* __restrict__ batch,
                                  const float* __restrict__ W2,
                                  const float* __restrict__ b2,
                                  float* __restrict__ out, int N) {
    int g = blockIdx.x, o = threadIdx.x;
    int s = lbound(batch, N, g);
    int e = lbound(batch, N, g + 1);
    float inv_cnt = 1.0f / fmaxf((float)(e - s), 1.0f);
    float acc = 0.f;
#pragma unroll 4
    for (int k = 0; k < D; ++k)
        acc = fmaf(pool[g * D + k], W2[k * D + o], acc);
    out[g * D + o] = acc * inv_cnt + b2[o];
}

// ---------------------------------------------------------------------------

extern "C" void kernel_launch(void* const* d_in, const int* in_sizes, int n_in,
                              void* d_out, int out_size, void* d_ws, size_t ws_size,
                              hipStream_t stream) {
    const float* x     = (const float*)d_in[0];
    const int*   ei    = (const int*)  d_in[1];
    const int*   batch = (const int*)  d_in[2];
    const float* W1    = (const float*)d_in[3];
    const float* b1    = (const float*)d_in[4];
    const float* W2    = (const float*)d_in[5];
    const float* b2    = (const float*)d_in[6];
    float* out = (float*)d_out;

    const int N = in_sizes[0] / D;
    const int E = in_sizes[1] / 2;
    const int nbuck = (N + BUCK_W - 1) >> BUCK_SH;      // <=128 for N<=65536
    const int CAP   = (E / (nbuck > 0 ? nbuck : 1)) * 2 + 1024;

    // workspace carve-up (256B aligned); bcnt+pool+ticket -> single memset
    char* ws = (char*)d_ws;
    size_t off = 0;
    auto carve = [&](size_t bytes) {
        size_t o = off;
        off = (off + bytes + 255) & ~(size_t)255;
        return o;
    };
    size_t o_bcnt     = carve((size_t)MAXBUCK * 4);
    size_t o_pool     = carve((size_t)NGRAPH * D * 4);
    size_t o_ticket   = carve((size_t)256);
    size_t zspan      = off;                       // memset [0, zspan)
    size_t o_rowstart = carve((size_t)(N + 1) * 4);
    size_t o_deg      = carve((size_t)N * 4);
    size_t o_dinv     = carve((size_t)N * 4);
    size_t o_padsum   = carve((size_t)MAXBUCK * 4);
    size_t o_bbase    = carve((size_t)MAXBUCK * 4);
    size_t o_colidx   = carve(((size_t)E + 7 * (size_t)N + 64) * 2);  // padded
    size_t o_buck     = carve((size_t)nbuck * CAP * 4);
    size_t o_wb       = carve((size_t)D * D * 2);        // fp16 W1 (MFMA B)
    size_t o_gh       = carve((size_t)(N + 1) * D * 2);  // fp16 G' panel-major
    size_t o_hh       = carve((size_t)(N + 1) * D * 2);  // fp16 H'' panel-major
    size_t need = off;

    if (ws_size < need) {
        zero_out_kernel<<<(out_size + 255) / 256, 256, 0, stream>>>(out, out_size);
        return;
    }

    int*            bcnt     = (int*)           (ws + o_bcnt);
    float*          pool     = (float*)         (ws + o_pool);
    int*            ticket   = (int*)           (ws + o_ticket);
    int*            rowstart = (int*)           (ws + o_rowstart);
    int*            deg      = (int*)           (ws + o_deg);
    float*          dinv     = (float*)         (ws + o_dinv);
    int*            padsum   = (int*)           (ws + o_padsum);
    int*            bbase    = (int*)           (ws + o_bbase);
    unsigned short* colidx   = (unsigned short*)(ws + o_colidx);
    unsigned*       buck     = (unsigned*)      (ws + o_buck);
    _Float16*       WB       = (_Float16*)      (ws + o_wb);
    _Float16*       Gh       = (_Float16*)      (ws + o_gh);
    _Float16*       Hh       = (_Float16*)      (ws + o_hh);

    hipMemsetAsync(ws, 0, zspan, stream);          // bcnt + pool + ticket

    int ebs = (E + 1023) / 1024;                   // scatter: 4 edges/thread
    int gb  = (N + 63) / 64;

    pack_scatter_kernel<<<9 + ebs, 256, 0, stream>>>(W1, WB, ei, bcnt, buck,
                                                     (unsigned*)Gh, (unsigned*)Hh,
                                                     N, E, CAP);
    bucket_deg_kernel<<<nbuck, 256, 0, stream>>>(buck, bcnt, deg, dinv, padsum,
                                                 bbase, rowstart, ticket,
                                                 N, CAP, nbuck);
    gemm_fill_kernel<<<gb + nbuck, 256, 0, stream>>>(x, WB, dinv, Gh, buck, bcnt,
                                                     deg, bbase, rowstart, colidx,
                                                     N, CAP, gb);

    // groups per panel = (AGG_BLOCKS/4)*4 = AGG_BLOCKS/... -> gid in [0,2048)
    int chunk = (N + AGG_BLOCKS - 1) / AGG_BLOCKS;
    agg1_kernel<<<AGG_BLOCKS, 256, 0, stream>>>((const unsigned*)Gh, rowstart, colidx,
                                                dinv, b1, (unsigned*)Hh, N, chunk);
    agg2_pool_kernel<<<AGG_BLOCKS, 256, 0, stream>>>((const unsigned*)Hh, rowstart, colidx,
                                                     dinv, batch, pool, N, chunk);
    final_gemm_kernel<<<NGRAPH, D, 0, stream>>>(pool, batch, W2, b2, out, N);
}

// Round 7
// 201.413 us; speedup vs baseline: 1.3383x; 1.3383x over previous
//
#include <hip/hip_runtime.h>

// ---------------------------------------------------------------------------
// 2-layer GCN + global mean pool, MI355X (gfx950).
//   A_hat = D^{-1/2}(A+I)D^{-1/2}
//   G' = dinv*(X @ W1) fp16 [MFMA fp16];  H'' = dinv*relu(dinv*A_sum(G')+b1)
//   out = pool(dinv*A_sum(H'')) @ W2 + b2
// R17 = R16 resubmit (infra failure) with the inline-asm v_fma_mix replaced
//   by __builtin_amdgcn_fdot2 (v_dot2_f32_f16; __has_builtin-guarded with
//   cvt+add fallback -> cannot fail compile). Bit-identical numerics:
//   h.lo*1 + h.hi*0 + acc, single rounding, no inf in data.
//   VALU-diet aggs (R15 post-mortem: VALUBusy 55%, HBM 4% -> issue-bound):
//   (1) 1-instr-per-half accumulate; (2) 32-bit saddr gathers
//   ((cc<<6)+lane over SGPR base); (3) 16-edge bursts.
//   CSR build: R14 two-level counting sort, zero per-edge global atomics;
//   ticket-fused bucket scan (-1 launch).
// ws_size is 256 MiB; we use ~35 MB.
// ---------------------------------------------------------------------------

#define D 128
#define NGRAPH 64
#define AGG_BLOCKS 2048   // 8192 waves = 32/CU
#define BUCK_SH 9         // bucket = dst >> 9 (width 512)
#define BUCK_W  512
#define MAXBUCK 128       // N <= 65536

typedef _Float16 h16x2 __attribute__((ext_vector_type(2)));
typedef _Float16 f16x8 __attribute__((ext_vector_type(8)));
typedef float    f32x4 __attribute__((ext_vector_type(4)));
typedef unsigned short u16x8 __attribute__((ext_vector_type(8)));

__device__ __forceinline__ float2 h2f(unsigned u) {
    h16x2 h = __builtin_bit_cast(h16x2, u);
    return make_float2((float)h.x, (float)h.y);
}
__device__ __forceinline__ unsigned f2h(float x, float y) {
    h16x2 h;
    h.x = (_Float16)x;
    h.y = (_Float16)y;
    return __builtin_bit_cast(unsigned, h);
}
// acc.x += (f32)lo_f16(u); acc.y += (f32)hi_f16(u) — one v_dot2_f32_f16 each.
__device__ __forceinline__ void fmix2(float& ax, float& ay, unsigned u) {
    h16x2 h = __builtin_bit_cast(h16x2, u);
#if __has_builtin(__builtin_amdgcn_fdot2)
    const h16x2 onelo = {(_Float16)1.0f, (_Float16)0.0f};
    const h16x2 onehi = {(_Float16)0.0f, (_Float16)1.0f};
    ax = __builtin_amdgcn_fdot2(h, onelo, ax, false);
    ay = __builtin_amdgcn_fdot2(h, onehi, ay, false);
#else
    ax += (float)h.x;
    ay += (float)h.y;
#endif
}

// --- diagnostic: all-zero output (ws too small) ----------------------------
__global__ void zero_out_kernel(float* __restrict__ out, int n) {
    int i = blockIdx.x * blockDim.x + threadIdx.x;
    if (i < n) out[i] = 0.f;
}

// --- K1: W1 pack (blocks 0..7) | zero sentinel rows (block 8) | bucket
//     scatter (blocks 9..): LDS histogram + per-block span reservation. -----
__global__ __launch_bounds__(256) void pack_scatter_kernel(const float* __restrict__ W1,
                                                           _Float16* __restrict__ WB,
                                                           const int* __restrict__ ei,
                                                           int* __restrict__ bcnt,
                                                           unsigned* __restrict__ buck,
                                                           unsigned* __restrict__ Gz,
                                                           unsigned* __restrict__ Hz,
                                                           int N, int E, int CAP) {
    int b = (int)blockIdx.x;
    int t = (int)threadIdx.x;
    if (b < 8) {
        // WB[((kt*8+nt)*64+lane)*8+j] = W1[(kt*32+(lane>>4)*8+j)*D + nt*16+(lane&15)]
        int idx = b * 256 + t;                         // 0..2047
        int lane = idx & 63;
        int nt   = (idx >> 6) & 7;
        int kt   = idx >> 9;
        int col  = nt * 16 + (lane & 15);
        int krow = kt * 32 + (lane >> 4) * 8;
#pragma unroll
        for (int j = 0; j < 8; ++j)
            WB[idx * 8 + j] = (_Float16)W1[(krow + j) * D + col];
        return;
    }
    if (b == 8) {
        if (t < 64)       Gz[(size_t)N * 64 + t] = 0u;          // Gh row N = 0
        else if (t < 128) Hz[(size_t)N * 64 + (t - 64)] = 0u;   // Hh row N = 0
        return;
    }
    __shared__ unsigned histL[MAXBUCK];
    __shared__ int      baseL[MAXBUCK];
    if (t < MAXBUCK) histL[t] = 0u;
    __syncthreads();

    int e0 = (b - 9) * 1024;
    int bid[4];
    unsigned lidx[4], pk[4];
#pragma unroll
    for (int j = 0; j < 4; ++j) {
        int e = e0 + t + j * 256;
        bid[j] = -1;
        if (e < E) {
            int s = ei[e];
            int d = ei[E + e];
            if (d >= 0 && d < N) {
                s = min(max(s, 0), N - 1);
                bid[j] = d >> BUCK_SH;
                pk[j]  = ((unsigned)d << 16) | (unsigned)s;
            }
        }
    }
#pragma unroll
    for (int j = 0; j < 4; ++j)
        if (bid[j] >= 0) lidx[j] = atomicAdd(&histL[bid[j]], 1u);
    __syncthreads();
    if (t < MAXBUCK && histL[t] > 0u)
        baseL[t] = atomicAdd(&bcnt[t], (int)histL[t]);
    __syncthreads();
#pragma unroll
    for (int j = 0; j < 4; ++j)
        if (bid[j] >= 0) {
            int slot = baseL[bid[j]] + (int)lidx[j];
            if (slot < CAP) buck[(size_t)bid[j] * CAP + slot] = pk[j];
        }
}

// --- K2: per-bucket degree count (LDS atomics) -> deg, dinv, padsum;
//     LAST block (ticket) also scans padsums -> bbase, rowstart[N]. ---------
__global__ __launch_bounds__(256) void bucket_deg_kernel(const unsigned* __restrict__ buck,
                                                         const int* __restrict__ bcnt,
                                                         int* __restrict__ deg,
                                                         float* __restrict__ dinv,
                                                         int* __restrict__ padsum,
                                                         int* __restrict__ bbase,
                                                         int* __restrict__ rowstart,
                                                         int* __restrict__ ticket,
                                                         int N, int CAP, int nbuck) {
    __shared__ int degL[BUCK_W];
    __shared__ int red[256];
    __shared__ int lastFlag;
    int b = (int)blockIdx.x;
    int t = (int)threadIdx.x;
    for (int k = t; k < BUCK_W; k += 256) degL[k] = 0;
    __syncthreads();
    int cnt = min(bcnt[b], CAP);
    const unsigned* bp = buck + (size_t)b * CAP;
    for (int i = t; i < cnt; i += 256)
        atomicAdd(&degL[(bp[i] >> 16) & (BUCK_W - 1)], 1);
    __syncthreads();
    int base = b << BUCK_SH;
    int local = 0;
    for (int k = t; k < BUCK_W; k += 256) {
        int d = base + k;
        if (d < N) {
            int dg = degL[k];
            deg[d]  = dg;
            dinv[d] = rsqrtf((float)dg + 1.0f);
            local  += (dg + 7) & ~7;
        }
    }
    red[t] = local;
    __syncthreads();
    for (int off = 128; off > 0; off >>= 1) {
        if (t < off) red[t] += red[t + off];
        __syncthreads();
    }
    if (t == 0) padsum[b] = red[0];
    __threadfence();
    if (t == 0) lastFlag = (atomicAdd(ticket, 1) == nbuck - 1) ? 1 : 0;
    __syncthreads();
    if (lastFlag) {
        __threadfence();                     // acquire all padsum writes
        __shared__ int s[128];
        int own = (t < nbuck) ? padsum[t] : 0;
        if (t < 128) s[t] = own;
        __syncthreads();
        for (int off = 1; off < 128; off <<= 1) {
            int v = (t < 128 && t >= off) ? s[t - off] : 0;
            __syncthreads();
            if (t < 128) s[t] += v;
            __syncthreads();
        }
        if (t < nbuck) bbase[t] = s[t] - own;        // exclusive
        if (t == 127) rowstart[N] = s[127];
    }
}

// --- K3: fused MFMA GEMM (blocks [0,gb)) + bucket CSR fill ([gb,gb+nbuck)) -
// Fill: per-bucket LDS scan of padded degrees -> rowstart; sentinel pads;
// colidx placement via LDS cursors. Zero global atomics.
__global__ __launch_bounds__(256) void gemm_fill_kernel(const float* __restrict__ X,
                                                        const _Float16* __restrict__ WB,
                                                        const float* __restrict__ dinv,
                                                        _Float16* __restrict__ Gh,
                                                        const unsigned* __restrict__ buck,
                                                        const int* __restrict__ bcnt,
                                                        const int* __restrict__ deg,
                                                        const int* __restrict__ bbase,
                                                        int* __restrict__ rowstart,
                                                        unsigned short* __restrict__ colidx,
                                                        int N, int CAP, int gb) {
    if ((int)blockIdx.x >= gb) {
        __shared__ int degS[BUCK_W];    // deg, later absolute cursors
        __shared__ int loff[BUCK_W];
        __shared__ int sc[256];
        int b = (int)blockIdx.x - gb;
        int t = (int)threadIdx.x;
        int base_d = b << BUCK_SH;
        for (int k = t; k < BUCK_W; k += 256) {
            int d = base_d + k;
            degS[k] = (d < N) ? deg[d] : 0;
        }
        __syncthreads();
        // scan pad8 over 512 entries: thread t owns 2t, 2t+1
        int p0 = (degS[2 * t] + 7) & ~7;
        int p1 = (degS[2 * t + 1] + 7) & ~7;
        int own = p0 + p1;
        sc[t] = own;
        __syncthreads();
        for (int off = 1; off < 256; off <<= 1) {
            int v = (t >= off) ? sc[t - off] : 0;
            __syncthreads();
            sc[t] += v;
            __syncthreads();
        }
        int excl = sc[t] - own;
        loff[2 * t]     = excl;
        loff[2 * t + 1] = excl + p0;
        __syncthreads();
        int bb = bbase[b];
        // rowstart + sentinel pads (uses degS as degrees still)
        for (int k = t; k < BUCK_W; k += 256) {
            int d = base_d + k;
            if (d < N) {
                int rs = bb + loff[k];
                rowstart[d] = rs;
                int dg = degS[k];
                int p8 = (dg + 7) & ~7;
                for (int j = dg; j < p8; ++j)
                    colidx[rs + j] = (unsigned short)N;   // sentinel -> zero row
            }
        }
        __syncthreads();
        // convert degS -> absolute cursors
        for (int k = t; k < BUCK_W; k += 256) degS[k] = bb + loff[k];
        __syncthreads();
        int cnt = min(bcnt[b], CAP);
        const unsigned* bp = buck + (size_t)b * CAP;
        for (int i = t; i < cnt; i += 256) {
            unsigned u = bp[i];
            int ld = (int)((u >> 16) & (BUCK_W - 1));
            int slot = atomicAdd(&degS[ld], 1);           // LDS atomic
            colidx[slot] = (unsigned short)(u & 0xffffu);
        }
        return;
    }

    int t = (int)threadIdx.x;
    int wave = t >> 6, lane = t & 63;
    int mbase = blockIdx.x * 64 + wave * 16;
    int arow  = mbase + (lane & 15);
    if (arow >= N) arow = N - 1;             // clamped duplicate reads
    int kgrp  = lane >> 4;                   // 0..3

    // A-frag: lane holds X[arow][kt*32 + kgrp*8 .. +8], converted to fp16
    f16x8 afrag[4];
#pragma unroll
    for (int kt = 0; kt < 4; ++kt) {
        const float* xp = X + (size_t)arow * D + kt * 32 + kgrp * 8;
        float4 a0 = *(const float4*)xp;
        float4 a1 = *(const float4*)(xp + 4);
        f16x8 af;
        af[0] = (_Float16)a0.x; af[1] = (_Float16)a0.y;
        af[2] = (_Float16)a0.z; af[3] = (_Float16)a0.w;
        af[4] = (_Float16)a1.x; af[5] = (_Float16)a1.y;
        af[6] = (_Float16)a1.z; af[7] = (_Float16)a1.w;
        afrag[kt] = af;
    }
    f32x4 acc[8];
#pragma unroll
    for (int nt = 0; nt < 8; ++nt) acc[nt] = (f32x4){0.f, 0.f, 0.f, 0.f};
#pragma unroll
    for (int kt = 0; kt < 4; ++kt) {
#pragma unroll
        for (int nt = 0; nt < 8; ++nt) {
            uint4 u = *(const uint4*)(WB + (((kt * 8 + nt) * 64 + lane) * 8));
            f16x8 bfrag = __builtin_bit_cast(f16x8, u);
            acc[nt] = __builtin_amdgcn_mfma_f32_16x16x32_f16(afrag[kt], bfrag, acc[nt], 0, 0, 0);
        }
    }
    // C/D: col = lane&15, row = kgrp*4 + reg   [m89-verified, dtype-indep]
    int r0 = mbase + kgrp * 4;
#pragma unroll
    for (int r = 0; r < 4; ++r) {
        int row = r0 + r;
        if (row < N) {
            float dv = dinv[row];
#pragma unroll
            for (int nt = 0; nt < 8; ++nt)
                Gh[(size_t)row * D + nt * 16 + (lane & 15)] = (_Float16)(dv * acc[nt][r]);
        }
    }
}

// --- agg1: H''_i = dinv_i * relu(dinv_i*(sum_e G'_s + G'_i) + b1), fp16 -----
// 64-lane wave per node; padded CSR -> branchless 16/8-deep gather bursts.
// 32-bit offset gathers + dot2 accumulation (VALU diet).
__global__ __launch_bounds__(256) void agg1_kernel(const unsigned* __restrict__ Gh,
                                                   const int* __restrict__ rowstart,
                                                   const unsigned short* __restrict__ colidx,
                                                   const float* __restrict__ dinv,
                                                   const float* __restrict__ b1,
                                                   unsigned* __restrict__ Hh,
                                                   int N, int chunk) {
    int gid  = blockIdx.x * 4 + (threadIdx.x >> 6);
    unsigned lane = threadIdx.x & 63;
    int i0 = gid * chunk, i1 = min(i0 + chunk, N);
    float bx = b1[2 * lane], by = b1[2 * lane + 1];
    for (int i = i0; i < i1; ++i) {
        float di = dinv[i];
        float ax = 0.f, ay = 0.f;
        fmix2(ax, ay, Gh[((unsigned)i << 6) + lane]);       // self term
        int e0 = rowstart[i], e1 = rowstart[i + 1];         // both mult of 8
        int e = e0;
        for (; e + 15 < e1; e += 16) {
            u16x8 c0 = *(const u16x8*)(colidx + e);         // 16B, aligned
            u16x8 c1 = *(const u16x8*)(colidx + e + 8);
            unsigned u[16];
#pragma unroll
            for (int j = 0; j < 8; ++j)
                u[j] = Gh[((unsigned)c0[j] << 6) + lane];
#pragma unroll
            for (int j = 0; j < 8; ++j)
                u[8 + j] = Gh[((unsigned)c1[j] << 6) + lane];
#pragma unroll
            for (int j = 0; j < 16; ++j) fmix2(ax, ay, u[j]);
        }
        for (; e < e1; e += 8) {
            u16x8 cc = *(const u16x8*)(colidx + e);
            unsigned u[8];
#pragma unroll
            for (int j = 0; j < 8; ++j)
                u[j] = Gh[((unsigned)cc[j] << 6) + lane];
#pragma unroll
            for (int j = 0; j < 8; ++j) fmix2(ax, ay, u[j]);
        }
        float hx = fmaxf(fmaf(di, ax, bx), 0.f) * di;       // H'' = dinv*relu
        float hy = fmaxf(fmaf(di, ay, by), 0.f) * di;
        Hh[((unsigned)i << 6) + lane] = f2h(hx, hy);
    }
}

// --- agg2 + pool: pool[batch_i] += dinv_i*(sum_e H''_s + H''_i) -------------
__global__ __launch_bounds__(256) void agg2_pool_kernel(const unsigned* __restrict__ Hh,
                                                        const int* __restrict__ rowstart,
                                                        const unsigned short* __restrict__ colidx,
                                                        const float* __restrict__ dinv,
                                                        const int* __restrict__ batch,
                                                        float* __restrict__ pool,
                                                        int N, int chunk) {
    int gid  = blockIdx.x * 4 + (threadIdx.x >> 6);
    unsigned lane = threadIdx.x & 63;
    int i0 = gid * chunk, i1 = min(i0 + chunk, N);
    if (i0 >= N) return;

    float2 pa = make_float2(0.f, 0.f);
    int cur = min(max(batch[i0], 0), NGRAPH - 1);
    for (int i = i0; i < i1; ++i) {
        float di = dinv[i];
        float ax = 0.f, ay = 0.f;
        fmix2(ax, ay, Hh[((unsigned)i << 6) + lane]);       // self term
        int e0 = rowstart[i], e1 = rowstart[i + 1];
        int e = e0;
        for (; e + 15 < e1; e += 16) {
            u16x8 c0 = *(const u16x8*)(colidx + e);
            u16x8 c1 = *(const u16x8*)(colidx + e + 8);
            unsigned u[16];
#pragma unroll
            for (int j = 0; j < 8; ++j)
                u[j] = Hh[((unsigned)c0[j] << 6) + lane];
#pragma unroll
            for (int j = 0; j < 8; ++j)
                u[8 + j] = Hh[((unsigned)c1[j] << 6) + lane];
#pragma unroll
            for (int j = 0; j < 16; ++j) fmix2(ax, ay, u[j]);
        }
        for (; e < e1; e += 8) {
            u16x8 cc = *(const u16x8*)(colidx + e);
            unsigned u[8];
#pragma unroll
            for (int j = 0; j < 8; ++j)
                u[j] = Hh[((unsigned)cc[j] << 6) + lane];
#pragma unroll
            for (int j = 0; j < 8; ++j) fmix2(ax, ay, u[j]);
        }
        int b = min(max(batch[i], 0), NGRAPH - 1);
        if (b != cur) {                                     // uniform per wave
            atomicAdd(&pool[(size_t)cur * D + 2 * lane], pa.x);
            atomicAdd(&pool[(size_t)cur * D + 2 * lane + 1], pa.y);
            pa = make_float2(0.f, 0.f);
            cur = b;
        }
        pa.x = fmaf(di, ax, pa.x);
        pa.y = fmaf(di, ay, pa.y);
    }
    atomicAdd(&pool[(size_t)cur * D + 2 * lane], pa.x);
    atomicAdd(&pool[(size_t)cur * D + 2 * lane + 1], pa.y);
}

// --- Final tiny GEMM: out[g][o] = (pool[g]/cnt_g) . W2[:,o] + b2[o] ---------
__device__ __forceinline__ int lbound(const int* __restrict__ a, int n, int v) {
    int lo = 0, hi = n;
    while (lo < hi) {
        int m = (lo + hi) >> 1;
        if (a[m] < v) lo = m + 1; else hi = m;
    }
    return lo;
}

__global__ void final_gemm_kernel(const float* __restrict__ pool,
                                  const int* __restrict__ batch,
                                  const float* __restrict__ W2,
                                  const float* __restrict__ b2,
                                  float* __restrict__ out, int N) {
    int g = blockIdx.x, o = threadIdx.x;
    int s = lbound(batch, N, g);
    int e = lbound(batch, N, g + 1);
    float inv_cnt = 1.0f / fmaxf((float)(e - s), 1.0f);
    float acc = 0.f;
#pragma unroll 4
    for (int k = 0; k < D; ++k)
        acc = fmaf(pool[g * D + k], W2[k * D + o], acc);
    out[g * D + o] = acc * inv_cnt + b2[o];
}

// ---------------------------------------------------------------------------

extern "C" void kernel_launch(void* const* d_in, const int* in_sizes, int n_in,
                              void* d_out, int out_size, void* d_ws, size_t ws_size,
                              hipStream_t stream) {
    const float* x     = (const float*)d_in[0];
    const int*   ei    = (const int*)  d_in[1];
    const int*   batch = (const int*)  d_in[2];
    const float* W1    = (const float*)d_in[3];
    const float* b1    = (const float*)d_in[4];
    const float* W2    = (const float*)d_in[5];
    const float* b2    = (const float*)d_in[6];
    float* out = (float*)d_out;

    const int N = in_sizes[0] / D;
    const int E = in_sizes[1] / 2;
    const int nbuck = (N + BUCK_W - 1) >> BUCK_SH;      // <=128 for N<=65536
    const int CAP   = (E / (nbuck > 0 ? nbuck : 1)) * 2 + 1024;

    // workspace carve-up (256B aligned); bcnt+pool+ticket -> single memset
    char* ws = (char*)d_ws;
    size_t off = 0;
    auto carve = [&](size_t bytes) {
        size_t o = off;
        off = (off + bytes + 255) & ~(size_t)255;
        return o;
    };
    size_t o_bcnt     = carve((size_t)MAXBUCK * 4);
    size_t o_pool     = carve((size_t)NGRAPH * D * 4);
    size_t o_ticket   = carve((size_t)256);
    size_t zspan      = off;                       // memset [0, zspan)
    size_t o_rowstart = carve((size_t)(N + 1) * 4);
    size_t o_deg      = carve((size_t)N * 4);
    size_t o_dinv     = carve((size_t)N * 4);
    size_t o_padsum   = carve((size_t)MAXBUCK * 4);
    size_t o_bbase    = carve((size_t)MAXBUCK * 4);
    size_t o_colidx   = carve(((size_t)E + 7 * (size_t)N + 64) * 2);  // padded
    size_t o_buck     = carve((size_t)nbuck * CAP * 4);
    size_t o_wb       = carve((size_t)D * D * 2);        // fp16 W1 (MFMA B)
    size_t o_gh       = carve((size_t)(N + 1) * D * 2);  // fp16 G' (+zero row)
    size_t o_hh       = carve((size_t)(N + 1) * D * 2);  // fp16 H'' (+zero row)
    size_t need = off;

    if (ws_size < need) {
        zero_out_kernel<<<(out_size + 255) / 256, 256, 0, stream>>>(out, out_size);
        return;
    }

    int*            bcnt     = (int*)           (ws + o_bcnt);
    float*          pool     = (float*)         (ws + o_pool);
    int*            ticket   = (int*)           (ws + o_ticket);
    int*            rowstart = (int*)           (ws + o_rowstart);
    int*            deg      = (int*)           (ws + o_deg);
    float*          dinv     = (float*)         (ws + o_dinv);
    int*            padsum   = (int*)           (ws + o_padsum);
    int*            bbase    = (int*)           (ws + o_bbase);
    unsigned short* colidx   = (unsigned short*)(ws + o_colidx);
    unsigned*       buck     = (unsigned*)      (ws + o_buck);
    _Float16*       WB       = (_Float16*)      (ws + o_wb);
    _Float16*       Gh       = (_Float16*)      (ws + o_gh);
    _Float16*       Hh       = (_Float16*)      (ws + o_hh);

    hipMemsetAsync(ws, 0, zspan, stream);          // bcnt + pool + ticket

    int ebs = (E + 1023) / 1024;                   // scatter: 4 edges/thread
    int gb  = (N + 63) / 64;

    pack_scatter_kernel<<<9 + ebs, 256, 0, stream>>>(W1, WB, ei, bcnt, buck,
                                                     (unsigned*)Gh, (unsigned*)Hh,
                                                     N, E, CAP);
    bucket_deg_kernel<<<nbuck, 256, 0, stream>>>(buck, bcnt, deg, dinv, padsum,
                                                 bbase, rowstart, ticket,
                                                 N, CAP, nbuck);
    gemm_fill_kernel<<<gb + nbuck, 256, 0, stream>>>(x, WB, dinv, Gh, buck, bcnt,
                                                     deg, bbase, rowstart, colidx,
                                                     N, CAP, gb);

    int groups = AGG_BLOCKS * 4;
    int chunk  = (N + groups - 1) / groups;
    agg1_kernel<<<AGG_BLOCKS, 256, 0, stream>>>((const unsigned*)Gh, rowstart, colidx,
                                                dinv, b1, (unsigned*)Hh, N, chunk);
    agg2_pool_kernel<<<AGG_BLOCKS, 256, 0, stream>>>((const unsigned*)Hh, rowstart, colidx,
                                                     dinv, batch, pool, N, chunk);
    final_gemm_kernel<<<NGRAPH, D, 0, stream>>>(pool, batch, W2, b2, out, N);
}